// Round 1
// baseline (37.871 us; speedup 1.0000x reference)
//
#include <hip/hip_runtime.h>

// Gaussian splatting preprocess: project 3D gaussians, 2D covariance, radii.
// One thread processes 4 gaussians so every global access is an aligned float4.

__global__ __launch_bounds__(256) void gauss_pre_kernel(
    const float* __restrict__ means,   // N*3
    const float* __restrict__ scales,  // N*3
    const float* __restrict__ rots,    // N*4
    const float* __restrict__ vm,      // 16 (row-major 4x4)
    const float* __restrict__ pm,      // 16
    const float* __restrict__ s_tanfovx,
    const float* __restrict__ s_tanfovy,
    const float* __restrict__ s_scmod,
    const int*   __restrict__ s_ih,
    const int*   __restrict__ s_iw,
    float* __restrict__ out,           // N
    int n)
{
    const int t  = blockIdx.x * blockDim.x + threadIdx.x;
    const int g0 = t * 4;
    if (g0 >= n) return;

    const float tanfovx = s_tanfovx[0];
    const float tanfovy = s_tanfovy[0];
    const float scmod   = s_scmod[0];
    const float H = (float)s_ih[0];
    const float W = (float)s_iw[0];
    const float focal_x = W / (2.0f * tanfovx);
    const float focal_y = H / (2.0f * tanfovy);
    const float limx = 1.3f * tanfovx;
    const float limy = 1.3f * tanfovy;
    const float gx = (W + 15.0f) * 0.0625f;   // /16 is exact
    const float gy = (H + 15.0f) * 0.0625f;

    // uniform matrices
    float vmr[16], pmr[16];
    #pragma unroll
    for (int i = 0; i < 4; ++i) {
        float4 a = ((const float4*)vm)[i];
        vmr[4*i+0] = a.x; vmr[4*i+1] = a.y; vmr[4*i+2] = a.z; vmr[4*i+3] = a.w;
        float4 b = ((const float4*)pm)[i];
        pmr[4*i+0] = b.x; pmr[4*i+1] = b.y; pmr[4*i+2] = b.z; pmr[4*i+3] = b.w;
    }

    float mm[12], ss[12], rr[16], res[4];
    const bool full = (g0 + 3 < n);
    if (full) {
        const float4* m4 = (const float4*)means  + (size_t)t * 3;
        const float4* s4 = (const float4*)scales + (size_t)t * 3;
        const float4* r4 = (const float4*)rots   + (size_t)t * 4;
        float4 a;
        a = m4[0]; mm[0]=a.x;  mm[1]=a.y;  mm[2]=a.z;  mm[3]=a.w;
        a = m4[1]; mm[4]=a.x;  mm[5]=a.y;  mm[6]=a.z;  mm[7]=a.w;
        a = m4[2]; mm[8]=a.x;  mm[9]=a.y;  mm[10]=a.z; mm[11]=a.w;
        a = s4[0]; ss[0]=a.x;  ss[1]=a.y;  ss[2]=a.z;  ss[3]=a.w;
        a = s4[1]; ss[4]=a.x;  ss[5]=a.y;  ss[6]=a.z;  ss[7]=a.w;
        a = s4[2]; ss[8]=a.x;  ss[9]=a.y;  ss[10]=a.z; ss[11]=a.w;
        a = r4[0]; rr[0]=a.x;  rr[1]=a.y;  rr[2]=a.z;  rr[3]=a.w;
        a = r4[1]; rr[4]=a.x;  rr[5]=a.y;  rr[6]=a.z;  rr[7]=a.w;
        a = r4[2]; rr[8]=a.x;  rr[9]=a.y;  rr[10]=a.z; rr[11]=a.w;
        a = r4[3]; rr[12]=a.x; rr[13]=a.y; rr[14]=a.z; rr[15]=a.w;
    } else {
        #pragma unroll
        for (int u = 0; u < 4; ++u) {
            const int g = g0 + u;
            if (g < n) {
                mm[3*u+0] = means[3*(size_t)g+0];
                mm[3*u+1] = means[3*(size_t)g+1];
                mm[3*u+2] = means[3*(size_t)g+2];
                ss[3*u+0] = scales[3*(size_t)g+0];
                ss[3*u+1] = scales[3*(size_t)g+1];
                ss[3*u+2] = scales[3*(size_t)g+2];
                rr[4*u+0] = rots[4*(size_t)g+0];
                rr[4*u+1] = rots[4*(size_t)g+1];
                rr[4*u+2] = rots[4*(size_t)g+2];
                rr[4*u+3] = rots[4*(size_t)g+3];
            } else {
                mm[3*u+0]=0.f; mm[3*u+1]=0.f; mm[3*u+2]=0.f;
                ss[3*u+0]=0.f; ss[3*u+1]=0.f; ss[3*u+2]=0.f;
                rr[4*u+0]=1.f; rr[4*u+1]=0.f; rr[4*u+2]=0.f; rr[4*u+3]=0.f;
            }
        }
    }

    #pragma unroll
    for (int u = 0; u < 4; ++u) {
        const float mx = mm[3*u+0], my = mm[3*u+1], mz = mm[3*u+2];

        // p_view = m @ view[:3,:3] + view[3,:3]
        const float pvx = mx*vmr[0] + my*vmr[4] + mz*vmr[8]  + vmr[12];
        const float pvy = mx*vmr[1] + my*vmr[5] + mz*vmr[9]  + vmr[13];
        const float tz  = mx*vmr[2] + my*vmr[6] + mz*vmr[10] + vmr[14];

        // p_hom = m @ proj[:3,:] + proj[3,:]  (z unused)
        const float hx = mx*pmr[0] + my*pmr[4] + mz*pmr[8]  + pmr[12];
        const float hy = mx*pmr[1] + my*pmr[5] + mz*pmr[9]  + pmr[13];
        const float hw = mx*pmr[3] + my*pmr[7] + mz*pmr[11] + pmr[15];
        const float pw  = 1.0f / (hw + 1e-7f);
        const float ppx = hx * pw;
        const float ppy = hy * pw;

        // quaternion (unnormalized, as in reference) -> R
        const float r = rr[4*u+0], x = rr[4*u+1], y = rr[4*u+2], z = rr[4*u+3];
        const float R00 = 1.0f - 2.0f*(y*y + z*z);
        const float R01 = 2.0f*(x*y - r*z);
        const float R02 = 2.0f*(x*z + r*y);
        const float R10 = 2.0f*(x*y + r*z);
        const float R11 = 1.0f - 2.0f*(x*x + z*z);
        const float R12 = 2.0f*(y*z - r*x);
        const float R20 = 2.0f*(x*z - r*y);
        const float R21 = 2.0f*(y*z + r*x);
        const float R22 = 1.0f - 2.0f*(x*x + y*y);

        // Sigma[i][j] = sum_k (scmod*s_k)^2 R[k][i] R[k][j]
        const float s0 = scmod * ss[3*u+0];
        const float s1 = scmod * ss[3*u+1];
        const float s2 = scmod * ss[3*u+2];
        const float q0 = s0*s0, q1 = s1*s1, q2 = s2*s2;
        const float Sg00 = q0*R00*R00 + q1*R10*R10 + q2*R20*R20;
        const float Sg01 = q0*R00*R01 + q1*R10*R11 + q2*R20*R21;
        const float Sg02 = q0*R00*R02 + q1*R10*R12 + q2*R20*R22;
        const float Sg11 = q0*R01*R01 + q1*R11*R11 + q2*R21*R21;
        const float Sg12 = q0*R01*R02 + q1*R11*R12 + q2*R21*R22;
        const float Sg22 = q0*R02*R02 + q1*R12*R12 + q2*R22*R22;

        // Jacobian (3x2), clipped
        const float itz = 1.0f / tz;
        const float txc = fminf(fmaxf(pvx * itz, -limx), limx) * tz;
        const float tyc = fminf(fmaxf(pvy * itz, -limy), limy) * tz;
        const float J00 = focal_x * itz;
        const float J11 = focal_y * itz;
        const float J20 = -(focal_x * txc) * itz * itz;
        const float J21 = -(focal_y * tyc) * itz * itz;

        // T2[i][k] = sum_j W3[i][j] * Jc[j][k];  Jc col0=(J00,0,J20), col1=(0,J11,J21)
        const float a0 = vmr[0]*J00 + vmr[2]*J20;   // T2[0][0]
        const float a1 = vmr[4]*J00 + vmr[6]*J20;   // T2[1][0]
        const float a2 = vmr[8]*J00 + vmr[10]*J20;  // T2[2][0]
        const float b0 = vmr[1]*J11 + vmr[2]*J21;   // T2[0][1]
        const float b1 = vmr[5]*J11 + vmr[6]*J21;   // T2[1][1]
        const float b2 = vmr[9]*J11 + vmr[10]*J21;  // T2[2][1]

        // cov2 = T2^T Sigma T2 (2x2, symmetric)
        const float u0 = Sg00*a0 + Sg01*a1 + Sg02*a2;
        const float u1 = Sg01*a0 + Sg11*a1 + Sg12*a2;
        const float u2 = Sg02*a0 + Sg12*a1 + Sg22*a2;
        const float w0 = Sg00*b0 + Sg01*b1 + Sg02*b2;
        const float w1 = Sg01*b0 + Sg11*b1 + Sg12*b2;
        const float w2 = Sg02*b0 + Sg12*b1 + Sg22*b2;
        const float cov00 = a0*u0 + a1*u1 + a2*u2;
        const float cov01 = b0*u0 + b1*u1 + b2*u2;
        const float cov11 = b0*w0 + b1*w1 + b2*w2;

        const float cov_x = cov00 + 0.3f;
        const float cov_y = cov01;
        const float cov_z = cov11 + 0.3f;
        const float det = cov_x*cov_z - cov_y*cov_y;
        const float mid = 0.5f*(cov_x + cov_z);
        const float lambda1 = mid + sqrtf(fmaxf(0.1f, mid*mid - det));
        const float radius = ceilf(3.0f * sqrtf(lambda1));

        const float pxs = ((ppx + 1.0f)*W - 1.0f)*0.5f;
        const float pys = ((ppy + 1.0f)*H - 1.0f)*0.5f;
        const float rminx = fminf(fmaxf(floorf((pxs - radius)*0.0625f), 0.0f), gx);
        const float rminy = fminf(fmaxf(floorf((pys - radius)*0.0625f), 0.0f), gy);
        const float rmaxx = fminf(fmaxf(floorf((pxs + radius + 15.0f)*0.0625f), 0.0f), gx);
        const float rmaxy = fminf(fmaxf(floorf((pys + radius + 15.0f)*0.0625f), 0.0f), gy);
        const float area = (rmaxx - rminx)*(rmaxy - rminy);

        const bool valid = (tz > 0.2f) && (det != 0.0f) && (area != 0.0f);
        res[u] = valid ? radius : 0.0f;
    }

    if (full) {
        float4 o; o.x = res[0]; o.y = res[1]; o.z = res[2]; o.w = res[3];
        ((float4*)out)[t] = o;
    } else {
        #pragma unroll
        for (int u = 0; u < 4; ++u) {
            if (g0 + u < n) out[g0 + u] = res[u];
        }
    }
}

extern "C" void kernel_launch(void* const* d_in, const int* in_sizes, int n_in,
                              void* d_out, int out_size, void* d_ws, size_t ws_size,
                              hipStream_t stream) {
    const float* means  = (const float*)d_in[0];
    const float* scales = (const float*)d_in[1];
    const float* rots   = (const float*)d_in[2];
    const float* vm     = (const float*)d_in[3];
    const float* pm     = (const float*)d_in[4];
    const float* tfx    = (const float*)d_in[5];
    const float* tfy    = (const float*)d_in[6];
    const float* scm    = (const float*)d_in[7];
    const int*   ih     = (const int*)d_in[8];
    const int*   iw     = (const int*)d_in[9];
    float* out = (float*)d_out;

    const int n  = in_sizes[0] / 3;          // N gaussians
    const int n4 = (n + 3) / 4;              // threads (4 gaussians each)
    dim3 block(256);
    dim3 grid((n4 + 255) / 256);
    hipLaunchKernelGGL(gauss_pre_kernel, grid, block, 0, stream,
                       means, scales, rots, vm, pm, tfx, tfy, scm, ih, iw, out, n);
}

// Round 2
// 33.581 us; speedup vs baseline: 1.1277x; 1.1277x over previous
//
#include <hip/hip_runtime.h>

// Gaussian splatting preprocess: project 3D gaussians, 2D covariance, radii.
// One thread processes 4 gaussians so every global access is an aligned float4.
// VALU-optimized: native rcp/sqrt, cov2 = (M*T2)^T (M*T2) factorization.

__device__ __forceinline__ float frcp(float x)  { return __builtin_amdgcn_rcpf(x); }
__device__ __forceinline__ float fsqrt(float x) { return __builtin_amdgcn_sqrtf(x); }

__global__ __launch_bounds__(256) void gauss_pre_kernel(
    const float* __restrict__ means,   // N*3
    const float* __restrict__ scales,  // N*3
    const float* __restrict__ rots,    // N*4
    const float* __restrict__ vm,      // 16 (row-major 4x4)
    const float* __restrict__ pm,      // 16
    const float* __restrict__ s_tanfovx,
    const float* __restrict__ s_tanfovy,
    const float* __restrict__ s_scmod,
    const int*   __restrict__ s_ih,
    const int*   __restrict__ s_iw,
    float* __restrict__ out,           // N
    int n)
{
    const int t  = blockIdx.x * blockDim.x + threadIdx.x;
    const int g0 = t * 4;
    if (g0 >= n) return;

    const float tanfovx = s_tanfovx[0];
    const float tanfovy = s_tanfovy[0];
    const float scmod   = s_scmod[0];
    const float H = (float)s_ih[0];
    const float W = (float)s_iw[0];
    const float focal_x = W * 0.5f * frcp(tanfovx);
    const float focal_y = H * 0.5f * frcp(tanfovy);
    const float limx = 1.3f * tanfovx;
    const float limy = 1.3f * tanfovy;
    const float gx = (W + 15.0f) * 0.0625f;   // /16 exact
    const float gy = (H + 15.0f) * 0.0625f;

    // uniform matrices (scalar loads — uniform address)
    float vmr[16], pmr[16];
    #pragma unroll
    for (int i = 0; i < 4; ++i) {
        float4 a = ((const float4*)vm)[i];
        vmr[4*i+0] = a.x; vmr[4*i+1] = a.y; vmr[4*i+2] = a.z; vmr[4*i+3] = a.w;
        float4 b = ((const float4*)pm)[i];
        pmr[4*i+0] = b.x; pmr[4*i+1] = b.y; pmr[4*i+2] = b.z; pmr[4*i+3] = b.w;
    }

    float mm[12], ss[12], rr[16], res[4];
    const bool full = (g0 + 3 < n);
    if (full) {
        const float4* m4 = (const float4*)means  + (size_t)t * 3;
        const float4* s4 = (const float4*)scales + (size_t)t * 3;
        const float4* r4 = (const float4*)rots   + (size_t)t * 4;
        float4 a;
        a = m4[0]; mm[0]=a.x;  mm[1]=a.y;  mm[2]=a.z;  mm[3]=a.w;
        a = m4[1]; mm[4]=a.x;  mm[5]=a.y;  mm[6]=a.z;  mm[7]=a.w;
        a = m4[2]; mm[8]=a.x;  mm[9]=a.y;  mm[10]=a.z; mm[11]=a.w;
        a = s4[0]; ss[0]=a.x;  ss[1]=a.y;  ss[2]=a.z;  ss[3]=a.w;
        a = s4[1]; ss[4]=a.x;  ss[5]=a.y;  ss[6]=a.z;  ss[7]=a.w;
        a = s4[2]; ss[8]=a.x;  ss[9]=a.y;  ss[10]=a.z; ss[11]=a.w;
        a = r4[0]; rr[0]=a.x;  rr[1]=a.y;  rr[2]=a.z;  rr[3]=a.w;
        a = r4[1]; rr[4]=a.x;  rr[5]=a.y;  rr[6]=a.z;  rr[7]=a.w;
        a = r4[2]; rr[8]=a.x;  rr[9]=a.y;  rr[10]=a.z; rr[11]=a.w;
        a = r4[3]; rr[12]=a.x; rr[13]=a.y; rr[14]=a.z; rr[15]=a.w;
    } else {
        #pragma unroll
        for (int u = 0; u < 4; ++u) {
            const int g = g0 + u;
            if (g < n) {
                mm[3*u+0] = means[3*(size_t)g+0];
                mm[3*u+1] = means[3*(size_t)g+1];
                mm[3*u+2] = means[3*(size_t)g+2];
                ss[3*u+0] = scales[3*(size_t)g+0];
                ss[3*u+1] = scales[3*(size_t)g+1];
                ss[3*u+2] = scales[3*(size_t)g+2];
                rr[4*u+0] = rots[4*(size_t)g+0];
                rr[4*u+1] = rots[4*(size_t)g+1];
                rr[4*u+2] = rots[4*(size_t)g+2];
                rr[4*u+3] = rots[4*(size_t)g+3];
            } else {
                mm[3*u+0]=0.f; mm[3*u+1]=0.f; mm[3*u+2]=0.f;
                ss[3*u+0]=0.f; ss[3*u+1]=0.f; ss[3*u+2]=0.f;
                rr[4*u+0]=1.f; rr[4*u+1]=0.f; rr[4*u+2]=0.f; rr[4*u+3]=0.f;
            }
        }
    }

    #pragma unroll
    for (int u = 0; u < 4; ++u) {
        const float mx = mm[3*u+0], my = mm[3*u+1], mz = mm[3*u+2];

        // p_view = m @ view[:3,:3] + view[3,:3]
        const float pvx = mx*vmr[0] + my*vmr[4] + mz*vmr[8]  + vmr[12];
        const float pvy = mx*vmr[1] + my*vmr[5] + mz*vmr[9]  + vmr[13];
        const float tz  = mx*vmr[2] + my*vmr[6] + mz*vmr[10] + vmr[14];

        // p_hom (x, y, w only)
        const float hx = mx*pmr[0] + my*pmr[4] + mz*pmr[8]  + pmr[12];
        const float hy = mx*pmr[1] + my*pmr[5] + mz*pmr[9]  + pmr[13];
        const float hw = mx*pmr[3] + my*pmr[7] + mz*pmr[11] + pmr[15];
        const float pw  = frcp(hw + 1e-7f);
        const float ppx = hx * pw;
        const float ppy = hy * pw;

        // clipped screen-space derivatives; J20 = -fx*tx/tz^2 = -fxz*cx
        const float itz = frcp(tz);
        const float cx  = fminf(fmaxf(pvx * itz, -limx), limx);
        const float cy  = fminf(fmaxf(pvy * itz, -limy), limy);
        const float fxz = focal_x * itz;
        const float fyz = focal_y * itz;

        // T2[:,0] = fxz * A, T2[:,1] = fyz * B
        const float A0 = vmr[0] - vmr[2]*cx;
        const float A1 = vmr[4] - vmr[6]*cx;
        const float A2 = vmr[8] - vmr[10]*cx;
        const float B0 = vmr[1] - vmr[2]*cy;
        const float B1 = vmr[5] - vmr[6]*cy;
        const float B2 = vmr[9] - vmr[10]*cy;

        // quaternion -> R (rows R[k][:])
        const float r = rr[4*u+0], x = rr[4*u+1], y = rr[4*u+2], z = rr[4*u+3];
        const float xx = x*x, yy = y*y, zz = z*z;
        const float xy = x*y, xz = x*z, yz = y*z;
        const float rx = r*x, ry = r*y, rz = r*z;
        const float R00 = 1.0f - 2.0f*(yy + zz);
        const float R01 = 2.0f*(xy - rz);
        const float R02 = 2.0f*(xz + ry);
        const float R10 = 2.0f*(xy + rz);
        const float R11 = 1.0f - 2.0f*(xx + zz);
        const float R12 = 2.0f*(yz - rx);
        const float R20 = 2.0f*(xz - ry);
        const float R21 = 2.0f*(yz + rx);
        const float R22 = 1.0f - 2.0f*(xx + yy);

        // cov2 = (M T2)^T (M T2),  M[k][:] = s_k * R[k][:]
        // e_k = s_k * (R[k]·A),  f_k = s_k * (R[k]·B)
        const float s0 = scmod * ss[3*u+0];
        const float s1 = scmod * ss[3*u+1];
        const float s2 = scmod * ss[3*u+2];
        const float e0 = s0 * (R00*A0 + R01*A1 + R02*A2);
        const float e1 = s1 * (R10*A0 + R11*A1 + R12*A2);
        const float e2 = s2 * (R20*A0 + R21*A1 + R22*A2);
        const float f0 = s0 * (R00*B0 + R01*B1 + R02*B2);
        const float f1 = s1 * (R10*B0 + R11*B1 + R12*B2);
        const float f2 = s2 * (R20*B0 + R21*B1 + R22*B2);
        const float ee = e0*e0 + e1*e1 + e2*e2;
        const float ef = e0*f0 + e1*f1 + e2*f2;
        const float ff = f0*f0 + f1*f1 + f2*f2;

        const float cov_x = fxz*fxz*ee + 0.3f;
        const float cov_y = fxz*fyz*ef;
        const float cov_z = fyz*fyz*ff + 0.3f;
        const float det = cov_x*cov_z - cov_y*cov_y;
        const float mid = 0.5f*(cov_x + cov_z);
        const float lambda1 = mid + fsqrt(fmaxf(0.1f, mid*mid - det));
        const float radius = ceilf(3.0f * fsqrt(lambda1));

        const float pxs = ((ppx + 1.0f)*W - 1.0f)*0.5f;
        const float pys = ((ppy + 1.0f)*H - 1.0f)*0.5f;
        const float rminx = fminf(fmaxf(floorf((pxs - radius)*0.0625f), 0.0f), gx);
        const float rminy = fminf(fmaxf(floorf((pys - radius)*0.0625f), 0.0f), gy);
        const float rmaxx = fminf(fmaxf(floorf((pxs + radius + 15.0f)*0.0625f), 0.0f), gx);
        const float rmaxy = fminf(fmaxf(floorf((pys + radius + 15.0f)*0.0625f), 0.0f), gy);
        const float area = (rmaxx - rminx)*(rmaxy - rminy);

        const bool valid = (tz > 0.2f) && (det != 0.0f) && (area != 0.0f);
        res[u] = valid ? radius : 0.0f;
    }

    if (full) {
        float4 o; o.x = res[0]; o.y = res[1]; o.z = res[2]; o.w = res[3];
        ((float4*)out)[t] = o;
    } else {
        #pragma unroll
        for (int u = 0; u < 4; ++u) {
            if (g0 + u < n) out[g0 + u] = res[u];
        }
    }
}

extern "C" void kernel_launch(void* const* d_in, const int* in_sizes, int n_in,
                              void* d_out, int out_size, void* d_ws, size_t ws_size,
                              hipStream_t stream) {
    const float* means  = (const float*)d_in[0];
    const float* scales = (const float*)d_in[1];
    const float* rots   = (const float*)d_in[2];
    const float* vm     = (const float*)d_in[3];
    const float* pm     = (const float*)d_in[4];
    const float* tfx    = (const float*)d_in[5];
    const float* tfy    = (const float*)d_in[6];
    const float* scm    = (const float*)d_in[7];
    const int*   ih     = (const int*)d_in[8];
    const int*   iw     = (const int*)d_in[9];
    float* out = (float*)d_out;

    const int n  = in_sizes[0] / 3;          // N gaussians
    const int n4 = (n + 3) / 4;              // threads (4 gaussians each)
    dim3 block(256);
    dim3 grid((n4 + 255) / 256);
    hipLaunchKernelGGL(gauss_pre_kernel, grid, block, 0, stream,
                       means, scales, rots, vm, pm, tfx, tfy, scm, ih, iw, out, n);
}

// Round 4
// 32.377 us; speedup vs baseline: 1.1697x; 1.0372x over previous
//
#include <hip/hip_runtime.h>

// Gaussian splatting preprocess: project 3D gaussians, 2D covariance, radii.
// One thread processes 4 gaussians; per-gaussian math is written as 4-wide
// ext_vector float ops so the compiler can select packed f32 (v_pk_fma_f32).

typedef float v4f __attribute__((ext_vector_type(4)));

__device__ __forceinline__ float frcp(float x)  { return __builtin_amdgcn_rcpf(x); }
__device__ __forceinline__ float fsqrt_(float x){ return __builtin_amdgcn_sqrtf(x); }

__device__ __forceinline__ v4f vrcp(v4f a) {
    v4f r; r.x = frcp(a.x); r.y = frcp(a.y); r.z = frcp(a.z); r.w = frcp(a.w); return r;
}
__device__ __forceinline__ v4f vsqrt(v4f a) {
    v4f r; r.x = fsqrt_(a.x); r.y = fsqrt_(a.y); r.z = fsqrt_(a.z); r.w = fsqrt_(a.w); return r;
}
__device__ __forceinline__ v4f vmaxs(v4f a, float b) {
    v4f r; r.x = fmaxf(a.x,b); r.y = fmaxf(a.y,b); r.z = fmaxf(a.z,b); r.w = fmaxf(a.w,b); return r;
}
__device__ __forceinline__ v4f vclamp(v4f a, float lo, float hi) {
    v4f r;
    r.x = fminf(fmaxf(a.x, lo), hi);
    r.y = fminf(fmaxf(a.y, lo), hi);
    r.z = fminf(fmaxf(a.z, lo), hi);
    r.w = fminf(fmaxf(a.w, lo), hi);
    return r;
}
__device__ __forceinline__ v4f vceil(v4f a) {
    v4f r; r.x = ceilf(a.x); r.y = ceilf(a.y); r.z = ceilf(a.z); r.w = ceilf(a.w); return r;
}

__global__ __launch_bounds__(256) void gauss_pre_kernel(
    const float* __restrict__ means,   // N*3
    const float* __restrict__ scales,  // N*3
    const float* __restrict__ rots,    // N*4
    const float* __restrict__ vm,      // 16 (row-major 4x4)
    const float* __restrict__ pm,      // 16
    const float* __restrict__ s_tanfovx,
    const float* __restrict__ s_tanfovy,
    const float* __restrict__ s_scmod,
    const int*   __restrict__ s_ih,
    const int*   __restrict__ s_iw,
    float* __restrict__ out,           // N
    int n)
{
    const int t  = blockIdx.x * blockDim.x + threadIdx.x;
    const int g0 = t * 4;
    if (g0 >= n) return;

    const float tanfovx = s_tanfovx[0];
    const float tanfovy = s_tanfovy[0];
    const float scmod   = s_scmod[0];
    const float H = (float)s_ih[0];
    const float W = (float)s_iw[0];
    const float focal_x = W * 0.5f * frcp(tanfovx);
    const float focal_y = H * 0.5f * frcp(tanfovy);
    const float limx = 1.3f * tanfovx;
    const float limy = 1.3f * tanfovy;
    const float gx = (W + 15.0f) * 0.0625f;   // /16 exact
    const float gy = (H + 15.0f) * 0.0625f;
    // area != 0 analytic thresholds (exact: /16 is exact, floor(t)>=c <=> t>=c)
    const float TX = 16.0f * ceilf(gx);
    const float TY = 16.0f * ceilf(gy);

    // uniform matrices (uniform address -> scalar loads)
    float vmr[16], pmr[16];
    #pragma unroll
    for (int i = 0; i < 4; ++i) {
        float4 a = ((const float4*)vm)[i];
        vmr[4*i+0] = a.x; vmr[4*i+1] = a.y; vmr[4*i+2] = a.z; vmr[4*i+3] = a.w;
        float4 b = ((const float4*)pm)[i];
        pmr[4*i+0] = b.x; pmr[4*i+1] = b.y; pmr[4*i+2] = b.z; pmr[4*i+3] = b.w;
    }

    float mm[12], ss[12], rr[16];
    const bool full = (g0 + 3 < n);
    if (full) {
        const float4* m4 = (const float4*)means  + (size_t)t * 3;
        const float4* s4 = (const float4*)scales + (size_t)t * 3;
        const float4* r4 = (const float4*)rots   + (size_t)t * 4;
        float4 a;
        a = m4[0]; mm[0]=a.x;  mm[1]=a.y;  mm[2]=a.z;  mm[3]=a.w;
        a = m4[1]; mm[4]=a.x;  mm[5]=a.y;  mm[6]=a.z;  mm[7]=a.w;
        a = m4[2]; mm[8]=a.x;  mm[9]=a.y;  mm[10]=a.z; mm[11]=a.w;
        a = s4[0]; ss[0]=a.x;  ss[1]=a.y;  ss[2]=a.z;  ss[3]=a.w;
        a = s4[1]; ss[4]=a.x;  ss[5]=a.y;  ss[6]=a.z;  ss[7]=a.w;
        a = s4[2]; ss[8]=a.x;  ss[9]=a.y;  ss[10]=a.z; ss[11]=a.w;
        a = r4[0]; rr[0]=a.x;  rr[1]=a.y;  rr[2]=a.z;  rr[3]=a.w;
        a = r4[1]; rr[4]=a.x;  rr[5]=a.y;  rr[6]=a.z;  rr[7]=a.w;
        a = r4[2]; rr[8]=a.x;  rr[9]=a.y;  rr[10]=a.z; rr[11]=a.w;
        a = r4[3]; rr[12]=a.x; rr[13]=a.y; rr[14]=a.z; rr[15]=a.w;
    } else {
        #pragma unroll
        for (int u = 0; u < 4; ++u) {
            const int g = g0 + u;
            if (g < n) {
                mm[3*u+0] = means[3*(size_t)g+0];
                mm[3*u+1] = means[3*(size_t)g+1];
                mm[3*u+2] = means[3*(size_t)g+2];
                ss[3*u+0] = scales[3*(size_t)g+0];
                ss[3*u+1] = scales[3*(size_t)g+1];
                ss[3*u+2] = scales[3*(size_t)g+2];
                rr[4*u+0] = rots[4*(size_t)g+0];
                rr[4*u+1] = rots[4*(size_t)g+1];
                rr[4*u+2] = rots[4*(size_t)g+2];
                rr[4*u+3] = rots[4*(size_t)g+3];
            } else {
                mm[3*u+0]=0.f; mm[3*u+1]=0.f; mm[3*u+2]=0.f;
                ss[3*u+0]=0.f; ss[3*u+1]=0.f; ss[3*u+2]=0.f;
                rr[4*u+0]=1.f; rr[4*u+1]=0.f; rr[4*u+2]=0.f; rr[4*u+3]=0.f;
            }
        }
    }

    // ---- transpose AoS -> 4-wide SoA vectors (register renaming, ~free) ----
    const v4f mx = {mm[0], mm[3], mm[6], mm[9]};
    const v4f my = {mm[1], mm[4], mm[7], mm[10]};
    const v4f mzv= {mm[2], mm[5], mm[8], mm[11]};
    const v4f qr = {rr[0], rr[4], rr[8], rr[12]};
    const v4f qx = {rr[1], rr[5], rr[9], rr[13]};
    const v4f qy = {rr[2], rr[6], rr[10], rr[14]};
    const v4f qz = {rr[3], rr[7], rr[11], rr[15]};
    const v4f s0 = scmod * (v4f){ss[0], ss[3], ss[6], ss[9]};
    const v4f s1 = scmod * (v4f){ss[1], ss[4], ss[7], ss[10]};
    const v4f s2 = scmod * (v4f){ss[2], ss[5], ss[8], ss[11]};

    // p_view
    const v4f pvx = mx*vmr[0] + my*vmr[4] + mzv*vmr[8]  + vmr[12];
    const v4f pvy = mx*vmr[1] + my*vmr[5] + mzv*vmr[9]  + vmr[13];
    const v4f tz  = mx*vmr[2] + my*vmr[6] + mzv*vmr[10] + vmr[14];

    // p_hom (x, y, w)
    const v4f hx = mx*pmr[0] + my*pmr[4] + mzv*pmr[8]  + pmr[12];
    const v4f hy = mx*pmr[1] + my*pmr[5] + mzv*pmr[9]  + pmr[13];
    const v4f hw = mx*pmr[3] + my*pmr[7] + mzv*pmr[11] + pmr[15];
    const v4f pw  = vrcp(hw + 1e-7f);
    const v4f ppx = hx * pw;
    const v4f ppy = hy * pw;

    // clipped screen derivatives
    const v4f itz = vrcp(tz);
    const v4f cx  = vclamp(pvx * itz, -limx, limx);
    const v4f cy  = vclamp(pvy * itz, -limy, limy);
    const v4f fxz = focal_x * itz;
    const v4f fyz = focal_y * itz;

    // T2[:,0] = fxz*A, T2[:,1] = fyz*B
    const v4f A0 = vmr[0] - vmr[2]*cx;
    const v4f A1 = vmr[4] - vmr[6]*cx;
    const v4f A2 = vmr[8] - vmr[10]*cx;
    const v4f B0 = vmr[1] - vmr[2]*cy;
    const v4f B1 = vmr[5] - vmr[6]*cy;
    const v4f B2 = vmr[9] - vmr[10]*cy;

    // quaternion -> R rows
    const v4f xx = qx*qx, yy = qy*qy, zz = qz*qz;
    const v4f xy = qx*qy, xz = qx*qz, yz = qy*qz;
    const v4f rx = qr*qx, ry = qr*qy, rz = qr*qz;
    const v4f R00 = 1.0f - 2.0f*(yy + zz);
    const v4f R01 = 2.0f*(xy - rz);
    const v4f R02 = 2.0f*(xz + ry);
    const v4f R10 = 2.0f*(xy + rz);
    const v4f R11 = 1.0f - 2.0f*(xx + zz);
    const v4f R12 = 2.0f*(yz - rx);
    const v4f R20 = 2.0f*(xz - ry);
    const v4f R21 = 2.0f*(yz + rx);
    const v4f R22 = 1.0f - 2.0f*(xx + yy);

    // cov2 = (M T2)^T (M T2), M[k][:] = s_k R[k][:]
    const v4f e0 = s0 * (R00*A0 + R01*A1 + R02*A2);
    const v4f e1 = s1 * (R10*A0 + R11*A1 + R12*A2);
    const v4f e2 = s2 * (R20*A0 + R21*A1 + R22*A2);
    const v4f f0 = s0 * (R00*B0 + R01*B1 + R02*B2);
    const v4f f1 = s1 * (R10*B0 + R11*B1 + R12*B2);
    const v4f f2 = s2 * (R20*B0 + R21*B1 + R22*B2);
    const v4f ee = e0*e0 + e1*e1 + e2*e2;
    const v4f ef = e0*f0 + e1*f1 + e2*f2;
    const v4f ff = f0*f0 + f1*f1 + f2*f2;

    const v4f cov_x = fxz*fxz*ee + 0.3f;
    const v4f cov_y = fxz*fyz*ef;
    const v4f cov_z = fyz*fyz*ff + 0.3f;
    const v4f det = cov_x*cov_z - cov_y*cov_y;
    const v4f mid = 0.5f*(cov_x + cov_z);
    const v4f lambda1 = mid + vsqrt(vmaxs(mid*mid - det, 0.1f));
    const v4f radius = vceil(3.0f * vsqrt(lambda1));

    const v4f pxs = ((ppx + 1.0f)*W - 1.0f)*0.5f;
    const v4f pys = ((ppy + 1.0f)*H - 1.0f)*0.5f;

    // analytic area!=0 test (exact equivalent of the floor/clamp formulation):
    // since radius>=3, raw floors always differ; area_x==0 iff fully clamped:
    //   px+radius+15 < 16  (both -> 0)   or   px-radius >= 16*ceil(gx) (both -> gx)
    v4f res;
    #pragma unroll
    for (int u = 0; u < 4; ++u) {
        const float rad = radius[u];
        const float pxu = pxs[u], pyu = pys[u];
        const bool vx = ((pxu + rad + 15.0f) >= 16.0f) && ((pxu - rad) < TX);
        const bool vy = ((pyu + rad + 15.0f) >= 16.0f) && ((pyu - rad) < TY);
        const bool valid = (tz[u] > 0.2f) && (det[u] != 0.0f) && vx && vy;
        res[u] = valid ? rad : 0.0f;
    }

    if (full) {
        __builtin_nontemporal_store(res, (v4f*)out + t);
    } else {
        #pragma unroll
        for (int u = 0; u < 4; ++u) {
            if (g0 + u < n) out[g0 + u] = res[u];
        }
    }
}

extern "C" void kernel_launch(void* const* d_in, const int* in_sizes, int n_in,
                              void* d_out, int out_size, void* d_ws, size_t ws_size,
                              hipStream_t stream) {
    const float* means  = (const float*)d_in[0];
    const float* scales = (const float*)d_in[1];
    const float* rots   = (const float*)d_in[2];
    const float* vm     = (const float*)d_in[3];
    const float* pm     = (const float*)d_in[4];
    const float* tfx    = (const float*)d_in[5];
    const float* tfy    = (const float*)d_in[6];
    const float* scm    = (const float*)d_in[7];
    const int*   ih     = (const int*)d_in[8];
    const int*   iw     = (const int*)d_in[9];
    float* out = (float*)d_out;

    const int n  = in_sizes[0] / 3;          // N gaussians
    const int n4 = (n + 3) / 4;              // threads (4 gaussians each)
    dim3 block(256);
    dim3 grid((n4 + 255) / 256);
    hipLaunchKernelGGL(gauss_pre_kernel, grid, block, 0, stream,
                       means, scales, rots, vm, pm, tfx, tfy, scm, ih, iw, out, n);
}

// Round 5
// 31.662 us; speedup vs baseline: 1.1961x; 1.0226x over previous
//
#include <hip/hip_runtime.h>

// Gaussian splatting preprocess: project 3D gaussians, 2D covariance, radii.
// One thread processes 8 gaussians (two 4-wide packed-f32 chunks): 20
// independent dwordx4 loads issue before the first waitcnt -> 2x memory-level
// parallelism per wave vs the 4-gaussian version (latency-bound fix).

typedef float v4f __attribute__((ext_vector_type(4)));

__device__ __forceinline__ float frcp(float x)  { return __builtin_amdgcn_rcpf(x); }
__device__ __forceinline__ float fsqrt_(float x){ return __builtin_amdgcn_sqrtf(x); }

__device__ __forceinline__ v4f vrcp(v4f a) {
    v4f r; r.x = frcp(a.x); r.y = frcp(a.y); r.z = frcp(a.z); r.w = frcp(a.w); return r;
}
__device__ __forceinline__ v4f vsqrt(v4f a) {
    v4f r; r.x = fsqrt_(a.x); r.y = fsqrt_(a.y); r.z = fsqrt_(a.z); r.w = fsqrt_(a.w); return r;
}
__device__ __forceinline__ v4f vmaxs(v4f a, float b) {
    v4f r; r.x = fmaxf(a.x,b); r.y = fmaxf(a.y,b); r.z = fmaxf(a.z,b); r.w = fmaxf(a.w,b); return r;
}
__device__ __forceinline__ v4f vclamp(v4f a, float lo, float hi) {
    v4f r;
    r.x = fminf(fmaxf(a.x, lo), hi);
    r.y = fminf(fmaxf(a.y, lo), hi);
    r.z = fminf(fmaxf(a.z, lo), hi);
    r.w = fminf(fmaxf(a.w, lo), hi);
    return r;
}
__device__ __forceinline__ v4f vceil(v4f a) {
    v4f r; r.x = ceilf(a.x); r.y = ceilf(a.y); r.z = ceilf(a.z); r.w = ceilf(a.w); return r;
}

struct GaussChunk {
    v4f mx, my, mz;      // means (SoA over 4 gaussians)
    v4f qr, qx, qy, qz;  // quaternion
    v4f s0, s1, s2;      // pre-scaled scales
};

__device__ __forceinline__ v4f gauss_radii(
    const GaussChunk& c,
    const float* __restrict__ vmr, const float* __restrict__ pmr,
    float focal_x, float focal_y, float limx, float limy,
    float W, float H, float TX, float TY)
{
    // p_view
    const v4f pvx = c.mx*vmr[0] + c.my*vmr[4] + c.mz*vmr[8]  + vmr[12];
    const v4f pvy = c.mx*vmr[1] + c.my*vmr[5] + c.mz*vmr[9]  + vmr[13];
    const v4f tz  = c.mx*vmr[2] + c.my*vmr[6] + c.mz*vmr[10] + vmr[14];

    // p_hom (x, y, w)
    const v4f hx = c.mx*pmr[0] + c.my*pmr[4] + c.mz*pmr[8]  + pmr[12];
    const v4f hy = c.mx*pmr[1] + c.my*pmr[5] + c.mz*pmr[9]  + pmr[13];
    const v4f hw = c.mx*pmr[3] + c.my*pmr[7] + c.mz*pmr[11] + pmr[15];
    const v4f pw  = vrcp(hw + 1e-7f);
    const v4f ppx = hx * pw;
    const v4f ppy = hy * pw;

    // clipped screen derivatives
    const v4f itz = vrcp(tz);
    const v4f cx  = vclamp(pvx * itz, -limx, limx);
    const v4f cy  = vclamp(pvy * itz, -limy, limy);
    const v4f fxz = focal_x * itz;
    const v4f fyz = focal_y * itz;

    // T2[:,0] = fxz*A, T2[:,1] = fyz*B
    const v4f A0 = vmr[0] - vmr[2]*cx;
    const v4f A1 = vmr[4] - vmr[6]*cx;
    const v4f A2 = vmr[8] - vmr[10]*cx;
    const v4f B0 = vmr[1] - vmr[2]*cy;
    const v4f B1 = vmr[5] - vmr[6]*cy;
    const v4f B2 = vmr[9] - vmr[10]*cy;

    // quaternion -> R rows
    const v4f xx = c.qx*c.qx, yy = c.qy*c.qy, zz = c.qz*c.qz;
    const v4f xy = c.qx*c.qy, xz = c.qx*c.qz, yz = c.qy*c.qz;
    const v4f rx = c.qr*c.qx, ry = c.qr*c.qy, rz = c.qr*c.qz;
    const v4f R00 = 1.0f - 2.0f*(yy + zz);
    const v4f R01 = 2.0f*(xy - rz);
    const v4f R02 = 2.0f*(xz + ry);
    const v4f R10 = 2.0f*(xy + rz);
    const v4f R11 = 1.0f - 2.0f*(xx + zz);
    const v4f R12 = 2.0f*(yz - rx);
    const v4f R20 = 2.0f*(xz - ry);
    const v4f R21 = 2.0f*(yz + rx);
    const v4f R22 = 1.0f - 2.0f*(xx + yy);

    // cov2 = (M T2)^T (M T2), M[k][:] = s_k R[k][:]
    const v4f e0 = c.s0 * (R00*A0 + R01*A1 + R02*A2);
    const v4f e1 = c.s1 * (R10*A0 + R11*A1 + R12*A2);
    const v4f e2 = c.s2 * (R20*A0 + R21*A1 + R22*A2);
    const v4f f0 = c.s0 * (R00*B0 + R01*B1 + R02*B2);
    const v4f f1 = c.s1 * (R10*B0 + R11*B1 + R12*B2);
    const v4f f2 = c.s2 * (R20*B0 + R21*B1 + R22*B2);
    const v4f ee = e0*e0 + e1*e1 + e2*e2;
    const v4f ef = e0*f0 + e1*f1 + e2*f2;
    const v4f ff = f0*f0 + f1*f1 + f2*f2;

    const v4f cov_x = fxz*fxz*ee + 0.3f;
    const v4f cov_y = fxz*fyz*ef;
    const v4f cov_z = fyz*fyz*ff + 0.3f;
    const v4f det = cov_x*cov_z - cov_y*cov_y;
    const v4f mid = 0.5f*(cov_x + cov_z);
    const v4f lambda1 = mid + vsqrt(vmaxs(mid*mid - det, 0.1f));
    const v4f radius = vceil(3.0f * vsqrt(lambda1));

    const v4f pxs = ((ppx + 1.0f)*W - 1.0f)*0.5f;
    const v4f pys = ((ppy + 1.0f)*H - 1.0f)*0.5f;

    // analytic area!=0 test (exact equivalent of the floor/clamp formulation)
    v4f res;
    #pragma unroll
    for (int u = 0; u < 4; ++u) {
        const float rad = radius[u];
        const float pxu = pxs[u], pyu = pys[u];
        const bool vx = ((pxu + rad + 15.0f) >= 16.0f) && ((pxu - rad) < TX);
        const bool vy = ((pyu + rad + 15.0f) >= 16.0f) && ((pyu - rad) < TY);
        const bool valid = (tz[u] > 0.2f) && (det[u] != 0.0f) && vx && vy;
        res[u] = valid ? rad : 0.0f;
    }
    return res;
}

__global__ __launch_bounds__(256) void gauss_pre_kernel(
    const float* __restrict__ means,   // N*3
    const float* __restrict__ scales,  // N*3
    const float* __restrict__ rots,    // N*4
    const float* __restrict__ vm,      // 16 (row-major 4x4)
    const float* __restrict__ pm,      // 16
    const float* __restrict__ s_tanfovx,
    const float* __restrict__ s_tanfovy,
    const float* __restrict__ s_scmod,
    const int*   __restrict__ s_ih,
    const int*   __restrict__ s_iw,
    float* __restrict__ out,           // N
    int n)
{
    const int t  = blockIdx.x * blockDim.x + threadIdx.x;
    const int g0 = t * 8;
    if (g0 >= n) return;

    const float tanfovx = s_tanfovx[0];
    const float tanfovy = s_tanfovy[0];
    const float scmod   = s_scmod[0];
    const float H = (float)s_ih[0];
    const float W = (float)s_iw[0];
    const float focal_x = W * 0.5f * frcp(tanfovx);
    const float focal_y = H * 0.5f * frcp(tanfovy);
    const float limx = 1.3f * tanfovx;
    const float limy = 1.3f * tanfovy;
    const float gx = (W + 15.0f) * 0.0625f;   // /16 exact
    const float gy = (H + 15.0f) * 0.0625f;
    const float TX = 16.0f * ceilf(gx);
    const float TY = 16.0f * ceilf(gy);

    // uniform matrices (uniform address -> scalar loads)
    float vmr[16], pmr[16];
    #pragma unroll
    for (int i = 0; i < 4; ++i) {
        float4 a = ((const float4*)vm)[i];
        vmr[4*i+0] = a.x; vmr[4*i+1] = a.y; vmr[4*i+2] = a.z; vmr[4*i+3] = a.w;
        float4 b = ((const float4*)pm)[i];
        pmr[4*i+0] = b.x; pmr[4*i+1] = b.y; pmr[4*i+2] = b.z; pmr[4*i+3] = b.w;
    }

    GaussChunk ch[2];
    const bool full = (g0 + 7 < n);
    if (full) {
        // 20 independent dwordx4 loads — all issue before first use
        const float4* m4 = (const float4*)means  + (size_t)t * 6;
        const float4* s4 = (const float4*)scales + (size_t)t * 6;
        const float4* r4 = (const float4*)rots   + (size_t)t * 8;
        const float4 m0 = m4[0], m1 = m4[1], m2 = m4[2], m3 = m4[3], m5 = m4[4], m6 = m4[5];
        const float4 sA = s4[0], sB = s4[1], sC = s4[2], sD = s4[3], sE = s4[4], sF = s4[5];
        const float4 r0 = r4[0], r1 = r4[1], r2 = r4[2], r3 = r4[3];
        const float4 r5 = r4[4], r6 = r4[5], r7 = r4[6], r8 = r4[7];

        ch[0].mx = (v4f){m0.x, m0.w, m1.z, m2.y};
        ch[0].my = (v4f){m0.y, m1.x, m1.w, m2.z};
        ch[0].mz = (v4f){m0.z, m1.y, m2.x, m2.w};
        ch[1].mx = (v4f){m3.x, m3.w, m5.z, m6.y};
        ch[1].my = (v4f){m3.y, m5.x, m5.w, m6.z};
        ch[1].mz = (v4f){m3.z, m5.y, m6.x, m6.w};

        ch[0].s0 = scmod * (v4f){sA.x, sA.w, sB.z, sC.y};
        ch[0].s1 = scmod * (v4f){sA.y, sB.x, sB.w, sC.z};
        ch[0].s2 = scmod * (v4f){sA.z, sB.y, sC.x, sC.w};
        ch[1].s0 = scmod * (v4f){sD.x, sD.w, sE.z, sF.y};
        ch[1].s1 = scmod * (v4f){sD.y, sE.x, sE.w, sF.z};
        ch[1].s2 = scmod * (v4f){sD.z, sE.y, sF.x, sF.w};

        ch[0].qr = (v4f){r0.x, r1.x, r2.x, r3.x};
        ch[0].qx = (v4f){r0.y, r1.y, r2.y, r3.y};
        ch[0].qy = (v4f){r0.z, r1.z, r2.z, r3.z};
        ch[0].qz = (v4f){r0.w, r1.w, r2.w, r3.w};
        ch[1].qr = (v4f){r5.x, r6.x, r7.x, r8.x};
        ch[1].qx = (v4f){r5.y, r6.y, r7.y, r8.y};
        ch[1].qy = (v4f){r5.z, r6.z, r7.z, r8.z};
        ch[1].qz = (v4f){r5.w, r6.w, r7.w, r8.w};
    } else {
        #pragma unroll
        for (int h = 0; h < 2; ++h) {
            #pragma unroll
            for (int u = 0; u < 4; ++u) {
                const int g = g0 + h*4 + u;
                float mv[3] = {0.f, 0.f, 0.f};
                float sv[3] = {0.f, 0.f, 0.f};
                float qv[4] = {1.f, 0.f, 0.f, 0.f};
                if (g < n) {
                    mv[0] = means[3*(size_t)g+0];
                    mv[1] = means[3*(size_t)g+1];
                    mv[2] = means[3*(size_t)g+2];
                    sv[0] = scales[3*(size_t)g+0];
                    sv[1] = scales[3*(size_t)g+1];
                    sv[2] = scales[3*(size_t)g+2];
                    qv[0] = rots[4*(size_t)g+0];
                    qv[1] = rots[4*(size_t)g+1];
                    qv[2] = rots[4*(size_t)g+2];
                    qv[3] = rots[4*(size_t)g+3];
                }
                ch[h].mx[u] = mv[0]; ch[h].my[u] = mv[1]; ch[h].mz[u] = mv[2];
                ch[h].s0[u] = scmod*sv[0]; ch[h].s1[u] = scmod*sv[1]; ch[h].s2[u] = scmod*sv[2];
                ch[h].qr[u] = qv[0]; ch[h].qx[u] = qv[1];
                ch[h].qy[u] = qv[2]; ch[h].qz[u] = qv[3];
            }
        }
    }

    v4f res0 = gauss_radii(ch[0], vmr, pmr, focal_x, focal_y, limx, limy, W, H, TX, TY);
    v4f res1 = gauss_radii(ch[1], vmr, pmr, focal_x, focal_y, limx, limy, W, H, TX, TY);

    if (full) {
        __builtin_nontemporal_store(res0, (v4f*)out + 2*(size_t)t);
        __builtin_nontemporal_store(res1, (v4f*)out + 2*(size_t)t + 1);
    } else {
        #pragma unroll
        for (int u = 0; u < 4; ++u) {
            if (g0 + u < n) out[g0 + u] = res0[u];
        }
        #pragma unroll
        for (int u = 0; u < 4; ++u) {
            if (g0 + 4 + u < n) out[g0 + 4 + u] = res1[u];
        }
    }
}

extern "C" void kernel_launch(void* const* d_in, const int* in_sizes, int n_in,
                              void* d_out, int out_size, void* d_ws, size_t ws_size,
                              hipStream_t stream) {
    const float* means  = (const float*)d_in[0];
    const float* scales = (const float*)d_in[1];
    const float* rots   = (const float*)d_in[2];
    const float* vm     = (const float*)d_in[3];
    const float* pm     = (const float*)d_in[4];
    const float* tfx    = (const float*)d_in[5];
    const float* tfy    = (const float*)d_in[6];
    const float* scm    = (const float*)d_in[7];
    const int*   ih     = (const int*)d_in[8];
    const int*   iw     = (const int*)d_in[9];
    float* out = (float*)d_out;

    const int n  = in_sizes[0] / 3;          // N gaussians
    const int n8 = (n + 7) / 8;              // threads (8 gaussians each)
    dim3 block(256);
    dim3 grid((n8 + 255) / 256);
    hipLaunchKernelGGL(gauss_pre_kernel, grid, block, 0, stream,
                       means, scales, rots, vm, pm, tfx, tfy, scm, ih, iw, out, n);
}